// Round 14
// baseline (237.183 us; speedup 1.0000x reference)
//
#include <hip/hip_runtime.h>
#include <hip/hip_bf16.h>
#include <stdint.h>

typedef __bf16 bf16;
typedef __attribute__((ext_vector_type(8))) __bf16 bf16x8;
typedef __attribute__((ext_vector_type(4))) float f32x4;

#define DEVI __device__ __forceinline__

constexpr int Bz = 4, Sz = 2048, Dz = 512, Hz = 8, DKz = 64, DFFz = 2048;
constexpr int ROWSz = Bz * Sz;  // 8192
constexpr float EPSf = 1e-5f;
constexpr float C2f = 0.125f * 1.44269504088896f;  // 1/sqrt(DK) * log2(e)

// ---- async global->LDS, 16B per lane. LDS dest is wave-uniform base + lane*16.
DEVI void load_lds16(void* lds, const void* g) {
  __builtin_amdgcn_global_load_lds(
      (const __attribute__((address_space(1))) void*)(uintptr_t)(g),
      (__attribute__((address_space(3))) void*)(uint32_t)(uintptr_t)(lds),
      16, 0, 0);
}

// gfx950 cross-lane half-swaps (pure VALU; all lanes active in this kernel).
DEVI void permswap32(unsigned& x, unsigned& y) {
  asm("v_permlane32_swap_b32 %0, %1" : "+v"(x), "+v"(y));
}
DEVI void permswap16(unsigned& x, unsigned& y) {
  asm("v_permlane16_swap_b32 %0, %1" : "+v"(x), "+v"(y));
}

// T1 XCD-aware block remap (R13, measured -9.3us on the GEMM fleet).
// HW round-robins linear block id over 8 XCDs (xcd = lid%8). Remap so
// each XCD owns a CONTIGUOUS sid range sweeping bx fastest: blocks
// sharing an A row-panel (same by) land on one XCD -> A-panel + weight
// panel become XCD-L2-resident. Bijective when nblocks%8==0 (all our
// GEMM grids: 768/512/512/512).
DEVI void xcd_remap(int& bx, int& by) {
  const int gx = gridDim.x;
  const int nb = gx * gridDim.y;
  const int lid = blockIdx.y * gx + blockIdx.x;
  const int per = nb >> 3;  // nb % 8 == 0 at every call site
  const int sid = (lid & 7) * per + (lid >> 3);
  bx = sid % gx;
  by = sid / gx;
}

// =====================================================================
// GEMM (best measured mix):  C = A[M,K] @ Bt[N,K]^T  +bias.
// EPI 1: bf16 = acc+bias+f32resid      2: bf16 = relu(acc+bias)
// EPI 3: QKV: col<512 Q*C2 row-major; col<1024 K row-major;
//        col>=1024 V -> aux = Vt[(b*8+h)*64+dk][s] transposed (LDS
//        transpose epilogue, coalesced 128B runs).
// EPI 4: bf16 = acc+bias+bf16resid
// =====================================================================
template <int BM, int BK, int EPI>
__global__ __launch_bounds__(256, BM == 128 ? 4 : 3) void gemm_bt(
    const bf16* __restrict__ A, const bf16* __restrict__ Bt,
    const float* __restrict__ bias, const float* __restrict__ resid,
    const bf16* __restrict__ residb, bf16* __restrict__ aux,
    void* __restrict__ Cout, int M, int N, int K) {
  constexpr int BN = 128;
  constexpr int MI = BM / 32;          // m-frags per wave
  constexpr int RPI = 512 / BK;        // rows per 16B-issue (16 @BK32, 8 @BK64)
  constexpr int AISS = (BM / 4) / RPI; // A issues per wave
  constexpr int BISS = 32 / RPI;       // B issues per wave
  __shared__ alignas(16) bf16 sA[2][BM * BK];
  __shared__ alignas(16) bf16 sB[2][BN * BK];
  const int tid = threadIdx.x;
  const int lane = tid & 63;
  const int wv = tid >> 6;
  int bx, by;
  xcd_remap(bx, by);
  const int n0 = bx * BN;
  const int m0 = by * BM;

  const int srow = (BK == 32) ? (lane >> 2) : (lane >> 3);
  const int sch = (BK == 32) ? (((lane & 3) ^ (srow & 3)) * 8)
                             : (((lane & 7) ^ (srow & 7)) * 8);
  const bf16* gA = A + (size_t)(m0 + wv * (BM / 4) + srow) * K + sch;
  const bf16* gB = Bt + (size_t)(n0 + wv * 32 + srow) * K + sch;

  const int wm = (wv >> 1) * (BM / 2);
  const int wn = (wv & 1) * 64;
  const int fr = lane & 15;
  const int fq = lane >> 4;

  auto stage = [&](int buf, int k0) {
#pragma unroll
    for (int j = 0; j < AISS; ++j)
      load_lds16(sA[buf] + (wv * (BM / 4) + j * RPI) * BK, gA + (size_t)(j * RPI) * K + k0);
#pragma unroll
    for (int j = 0; j < BISS; ++j)
      load_lds16(sB[buf] + (wv * 32 + j * RPI) * BK, gB + (size_t)(j * RPI) * K + k0);
  };

  f32x4 acc[MI][4] = {};

  stage(0, 0);
  __syncthreads();  // barrier's vmcnt(0) drain completes tile 0

  const int niter = K / BK;
  for (int it = 0; it < niter; ++it) {
    const int cur = it & 1;
    if (it + 1 < niter) stage(cur ^ 1, (it + 1) * BK);
#pragma unroll
    for (int kk = 0; kk < BK / 32; ++kk) {
      const int fc = (BK == 32) ? ((fq ^ (fr & 3)) * 8)
                                : (((4 * kk + fq) ^ (fr & 7)) * 8);
      bf16x8 af[MI], bfr[4];
#pragma unroll
      for (int i = 0; i < MI; ++i)
        af[i] = *(const bf16x8*)(sA[cur] + (wm + i * 16 + fr) * BK + fc);
#pragma unroll
      for (int j = 0; j < 4; ++j)
        bfr[j] = *(const bf16x8*)(sB[cur] + (wn + j * 16 + fr) * BK + fc);
#pragma unroll
      for (int i = 0; i < MI; ++i)
#pragma unroll
        for (int j = 0; j < 4; ++j)
          acc[i][j] = __builtin_amdgcn_mfma_f32_16x16x32_bf16(af[i], bfr[j], acc[i][j], 0, 0, 0);
    }
    __syncthreads();  // readers done with cur + prefetch DMA drained
  }

  if (EPI == 3 && n0 >= 1024) {
    // ---- V epilogue: per-wave LDS transpose -> coalesced Vt stores.
    bf16* Tw = (wv < 2 ? (bf16*)sA : (bf16*)sB) + (wv & 1) * 4096;  // 8KB own
#pragma unroll
    for (int i = 0; i < MI; ++i) {
#pragma unroll
      for (int j = 0; j < 4; ++j) {
        const int col = n0 + wn + j * 16 + fr;
        const float bv = bias[col];
        bf16 pv[4];
#pragma unroll
        for (int r = 0; r < 4; ++r) pv[r] = (bf16)(acc[i][j][r] + bv);
        const int dk = j * 16 + fr;
        const int boff = dk * 128 + ((i * 32 + fq * 8) ^ ((fr & 7) << 4));
        *(uint2*)((char*)Tw + boff) = *(const uint2*)pv;
      }
    }
    asm volatile("s_waitcnt lgkmcnt(0)" ::: "memory");  // own writes visible
    const int hh = (n0 + wn - 1024) >> 6;
    const int rowbase = m0 + wm;
    const int bb = rowbase >> 11, s0b = rowbase & 2047;
#pragma unroll
    for (int p = 0; p < 8; ++p) {
      const int dk = p * 8 + (lane >> 3);
      const int o = lane & 7;
      const uint4 v = *(const uint4*)((const char*)Tw + dk * 128 + ((o ^ (dk & 7)) << 4));
      *(uint4*)(aux + (size_t)((bb * 8 + hh) * 64 + dk) * 2048 + s0b + o * 8) = v;
    }
  } else {
#pragma unroll
    for (int i = 0; i < MI; ++i) {
#pragma unroll
      for (int j = 0; j < 4; ++j) {
        const int col = n0 + wn + j * 16 + fr;
        const float bv = bias[col];
#pragma unroll
        for (int r = 0; r < 4; ++r) {
          const int row = m0 + wm + i * 16 + fq * 4 + r;
          const size_t idx = (size_t)row * N + col;
          float v = acc[i][j][r] + bv;
          if (EPI == 1) {
            ((bf16*)Cout)[idx] = (bf16)(v + resid[idx]);
          } else if (EPI == 2) {
            ((bf16*)Cout)[idx] = (bf16)(v > 0.f ? v : 0.f);
          } else if (EPI == 3) {
            ((bf16*)Cout)[idx] = (bf16)(col < 512 ? v * C2f : v);
          } else {
            ((bf16*)Cout)[idx] = (bf16)(v + (float)residb[idx]);
          }
        }
      }
    }
  }
}

// =====================================================================
// Deep-pipelined GEMM v2 (R14, FFN1): C = relu(A @ Bt^T + bias).
// R13 post-mortem: gemm_256 at BM=256/BN=256 ran 1 block/CU = 2
// waves/SIMD (issue-starved, ~13% over gemm_bt). Reshape BM=128/
// BN=256: grid 8x64 = 512 blocks = 2 blocks/CU = 4 waves/SIMD (2x
// TLP). Same verified fragment algebra; per-wave output 64x64
// (2M x 4N), acc 64 VGPR -> launch_bounds(512,4) satisfiable.
// LDS 72KB x 2 blocks = 144 <= 160.
// 3-buffer counted-vmcnt ledger (3 issues/tile: A x1 + B x2):
//   - buffer staged at tile t was last read at tile t-1, behind its
//     end barrier; tile t's reads guarded by end-of-(t-1) vmcnt(3)
//     +barrier (retires t's 3, keeps t+1's 3 in flight; never 0
//     mid-loop). Prologue: 6 issues, vmcnt(3) -> tile 0 resident.
// =====================================================================
__global__ __launch_bounds__(512, 4) void gemm_256(
    const bf16* __restrict__ A, const bf16* __restrict__ Bt,
    const float* __restrict__ bias, bf16* __restrict__ Cout,
    int M, int N, int K) {
  constexpr int BM = 128, BN = 256, BK = 32;
  __shared__ alignas(16) bf16 sA[3][BM * BK];  // 8KB each
  __shared__ alignas(16) bf16 sB[3][BN * BK];  // 16KB each
  const int tid = threadIdx.x, lane = tid & 63, wv = tid >> 6;  // wv 0..7
  const int wr = wv >> 2, wc = wv & 3;  // wave -> 64x64 output sub-tile
  int bx, by;
  xcd_remap(bx, by);
  const int n0 = bx * BN, m0 = by * BM;
  const int fr = lane & 15, fq = lane >> 4;

  // staging: one issue covers 128 rows (8 waves x 16)
  const int srow = lane >> 2;                      // 0..15
  const int sch = ((lane & 3) ^ (srow & 3)) * 8;   // pre-swizzled chunk
  const bf16* gA = A + (size_t)(m0 + wv * 16 + srow) * K + sch;
  const bf16* gB = Bt + (size_t)(n0 + wv * 16 + srow) * K + sch;

  auto stageA = [&](int buf, int k0) {
    load_lds16(sA[buf] + (wv * 16) * BK, gA + k0);
  };
  auto stageB = [&](int buf, int k0) {
    load_lds16(sB[buf] + (wv * 16) * BK, gB + k0);
    load_lds16(sB[buf] + (128 + wv * 16) * BK, gB + (size_t)128 * K + k0);
  };

  const int fc = (fq ^ (fr & 3)) * 8;  // read-side swizzle (row&3 == fr&3)

  f32x4 acc[4][4] = {};

  // prologue: tiles 0,1 staged (6 issues); tile 0's 3 retired
  stageA(0, 0);
  stageB(0, 0);
  stageA(1, BK);
  stageB(1, BK);
  asm volatile("s_waitcnt vmcnt(3)" ::: "memory");
  __builtin_amdgcn_s_barrier();
  asm volatile("" ::: "memory");

  const int niter = K / BK;  // 16 for FFN1
  int cur = 0;
  for (int t = 0; t < niter; ++t) {
    const bf16* a = sA[cur];
    const bf16* b = sB[cur];
    int nb = cur + 2;
    if (nb >= 3) nb -= 3;
    const bool pf = (t + 2 < niter);

    // ---- phase 0: B-frags (all 4, reused) + A-frags 0-1; stage A(t+2)
    bf16x8 bfr[4], af[2];
#pragma unroll
    for (int j = 0; j < 4; ++j)
      bfr[j] = *(const bf16x8*)(b + (wc * 64 + j * 16 + fr) * BK + fc);
#pragma unroll
    for (int i = 0; i < 2; ++i)
      af[i] = *(const bf16x8*)(a + (wr * 64 + i * 16 + fr) * BK + fc);
    if (pf) stageA(nb, (t + 2) * BK);
    __builtin_amdgcn_s_setprio(1);
#pragma unroll
    for (int i = 0; i < 2; ++i)
#pragma unroll
      for (int j = 0; j < 4; ++j)
        acc[i][j] = __builtin_amdgcn_mfma_f32_16x16x32_bf16(af[i], bfr[j], acc[i][j], 0, 0, 0);
    __builtin_amdgcn_s_setprio(0);
    __builtin_amdgcn_s_barrier();  // phase alignment
    asm volatile("" ::: "memory");

    // ---- phase 1: A-frags 2-3; stage B(t+2); tile-end counted sync
    bf16x8 af2[2];
#pragma unroll
    for (int i = 0; i < 2; ++i)
      af2[i] = *(const bf16x8*)(a + (wr * 64 + (2 + i) * 16 + fr) * BK + fc);
    if (pf) stageB(nb, (t + 2) * BK);
    __builtin_amdgcn_s_setprio(1);
#pragma unroll
    for (int i = 0; i < 2; ++i)
#pragma unroll
      for (int j = 0; j < 4; ++j)
        acc[2 + i][j] = __builtin_amdgcn_mfma_f32_16x16x32_bf16(af2[i], bfr[j], acc[2 + i][j], 0, 0, 0);
    __builtin_amdgcn_s_setprio(0);
    if (t + 1 < niter) {
      if (pf) asm volatile("s_waitcnt vmcnt(3)" ::: "memory");  // t+1 ready
      else    asm volatile("s_waitcnt vmcnt(0)" ::: "memory");  // drain tail
      __builtin_amdgcn_s_barrier();
      asm volatile("" ::: "memory");
    }
    cur = cur == 2 ? 0 : cur + 1;
  }

  // ---- epilogue: relu(acc + bias) -> bf16 (same mapping as gemm_bt)
#pragma unroll
  for (int i = 0; i < 4; ++i)
#pragma unroll
    for (int j = 0; j < 4; ++j) {
      const int col = n0 + wc * 64 + j * 16 + fr;
      const float bv = bias[col];
#pragma unroll
      for (int r = 0; r < 4; ++r) {
        const int row = m0 + wr * 64 + i * 16 + fq * 4 + r;
        float v = acc[i][j][r] + bv;
        Cout[(size_t)row * N + col] = (bf16)(v > 0.f ? v : 0.f);
      }
    }
}

// =====================================================================
// Flash attention v8 (R8, frozen best: 50.0us): t-split + 32 q/wave.
// 8-wave blocks: waves 0-3 tiles 0-15, waves 4-7 tiles 16-31, same
// 128 q-rows; partials merged via LDS (max-free softmax => pure sums).
// Grid 512, 16 waves/CU = 4/SIMD. MfmaUtil 26% = exactly algorithmic
// MFMA content; further gains need full HK 4-cluster co-design.
// =====================================================================
__global__ __launch_bounds__(512, 4) void flash_attn(
    const bf16* __restrict__ qkv, const bf16* __restrict__ Vt,
    bf16* __restrict__ ctx) {
  const int bid = blockIdx.x;
  const int qt = bid >> 5;         // 0..15, 128-row q tiles
  const int bh = bid & 31;         // bid%8 == h -> XCD pinning per head
  const int h = bh & 7;
  const int b = bh >> 3;
  const int q0 = qt * 128;
  const int tid = threadIdx.x, lane = tid & 63, wv = tid >> 6;  // wv 0..7
  const int g = wv >> 2;           // t-group: 0 -> tiles 0..15, 1 -> 16..31
  const int wg = wv & 3;           // wave in group; owns q rows wg*32..+31
  const int fr = lane & 15, fq = lane >> 4;
  const int xsw = fr & 7;

  __shared__ alignas(16) union SMem {
    struct { bf16 K[2][2][64 * 64]; bf16 V[2][2][64 * 64]; } kv;
    float mrg[4 * 64 * 35];  // 4 waves x 64 lanes x (32 acc + 2 l + pad)
  } sm;

  const int srow = lane >> 3;                // 0..7 within 8-row issue
  const int scol = ((lane & 7) ^ srow) * 8;  // swizzled chunk (elements)

  const bf16* gK = qkv + (size_t)(b * Sz + wg * 16 + srow) * 1536 + 512 + h * 64 + scol;
  const bf16* gV = Vt + (size_t)((b * 8 + h) * 64 + wg * 16 + srow) * Sz + scol;

  auto stage = [&](int p, int t) {
    const size_t t0 = (size_t)t * 64;
    load_lds16(sm.kv.K[g][p] + (wg * 16 + 0) * 64, gK + t0 * 1536);
    load_lds16(sm.kv.K[g][p] + (wg * 16 + 8) * 64, gK + (t0 + 8) * 1536);
    load_lds16(sm.kv.V[g][p] + (wg * 16 + 0) * 64, gV + t0);
    load_lds16(sm.kv.V[g][p] + (wg * 16 + 8) * 64, gV + (size_t)8 * Sz + t0);
  };

  stage(0, g * 16);  // tile 0 of own range

  const bf16* gQf = qkv + (size_t)(b * Sz + q0 + wg * 32 + fr) * 1536 + h * 64;
  bf16x8 qb[2][2];
  qb[0][0] = *(const bf16x8*)(gQf + fq * 8);
  qb[0][1] = *(const bf16x8*)(gQf + (fq + 4) * 8);
  qb[1][0] = *(const bf16x8*)(gQf + (size_t)16 * 1536 + fq * 8);
  qb[1][1] = *(const bf16x8*)(gQf + (size_t)16 * 1536 + (fq + 4) * 8);

  asm volatile("s_waitcnt vmcnt(0)" ::: "memory");  // qb + stage(0) landed
  __builtin_amdgcn_s_barrier();
  asm volatile("" ::: "memory");

  const int colc0 = (fq ^ xsw) * 8;
  const int colc1 = ((fq + 4) ^ xsw) * 8;
  int qsrc[4];
#pragma unroll
  for (int r = 0; r < 4; ++r) qsrc[r] = (fq * 4 + r) | (lane & 48);

  const f32x4 ZERO = {0.f, 0.f, 0.f, 0.f};
  float l_part[2] = {0.f, 0.f};
  f32x4 acc_o[2][4] = {};

  for (int st = 0; st < 16; ++st) {
    const int p = st & 1;
    if (st + 1 < 16) stage(p ^ 1, g * 16 + st + 1);

    const bf16* kb = sm.kv.K[g][p];
    const bf16* vb = sm.kv.V[g][p];

    bf16x8 kf[2][4];
#pragma unroll
    for (int j = 0; j < 4; ++j) {
      kf[0][j] = *(const bf16x8*)(kb + (j * 16 + fr) * 64 + colc0);
      kf[1][j] = *(const bf16x8*)(kb + (j * 16 + fr) * 64 + colc1);
    }
    f32x4 sc[2][4];
    __builtin_amdgcn_s_setprio(1);
#pragma unroll
    for (int s = 0; s < 2; ++s)
#pragma unroll
      for (int j = 0; j < 4; ++j) {
        f32x4 z = __builtin_amdgcn_mfma_f32_16x16x32_bf16(kf[0][j], qb[s][0], ZERO, 0, 0, 0);
        sc[s][j] = __builtin_amdgcn_mfma_f32_16x16x32_bf16(kf[1][j], qb[s][1], z, 0, 0, 0);
      }
    __builtin_amdgcn_s_setprio(0);

    bf16x8 pa[2][2];
#pragma unroll
    for (int s = 0; s < 2; ++s) {
      unsigned c0[4], c1[4];
      float rs = 0.f;
#pragma unroll
      for (int j = 0; j < 4; ++j) {
        float e0 = __builtin_amdgcn_exp2f(sc[s][j][0]);
        float e1 = __builtin_amdgcn_exp2f(sc[s][j][1]);
        float e2 = __builtin_amdgcn_exp2f(sc[s][j][2]);
        float e3 = __builtin_amdgcn_exp2f(sc[s][j][3]);
        rs += (e0 + e1) + (e2 + e3);
        union { bf16 hh[2]; unsigned u; } pka, pkb;
        pka.hh[0] = (bf16)e0; pka.hh[1] = (bf16)e1;  // v_cvt_pk_bf16_f32
        pkb.hh[0] = (bf16)e2; pkb.hh[1] = (bf16)e3;
        c0[j] = pka.u;
        c1[j] = pkb.u;
      }
      l_part[s] += rs;
#pragma unroll
      for (int kk = 0; kk < 2; ++kk) {
        unsigned x0 = c0[2 * kk], y0 = c0[2 * kk + 1];
        permswap32(x0, y0);
        permswap16(x0, y0);
        unsigned x1 = c1[2 * kk], y1 = c1[2 * kk + 1];
        permswap32(x1, y1);
        permswap16(x1, y1);
        union { unsigned u[4]; bf16x8 v; } pk;
        pk.u[0] = x0; pk.u[1] = x1; pk.u[2] = y0; pk.u[3] = y1;
        pa[s][kk] = pk.v;
      }
    }

    bf16x8 vf[2][4];
#pragma unroll
    for (int j = 0; j < 4; ++j) {
      vf[0][j] = *(const bf16x8*)(vb + (j * 16 + fr) * 64 + colc0);
      vf[1][j] = *(const bf16x8*)(vb + (j * 16 + fr) * 64 + colc1);
    }
    __builtin_amdgcn_s_setprio(1);
#pragma unroll
    for (int s = 0; s < 2; ++s)
#pragma unroll
      for (int kk = 0; kk < 2; ++kk)
#pragma unroll
        for (int j = 0; j < 4; ++j)
          acc_o[s][j] = __builtin_amdgcn_mfma_f32_16x16x32_bf16(pa[s][kk], vf[kk][j], acc_o[s][j], 0, 0, 0);
    __builtin_amdgcn_s_setprio(0);

    if (st + 1 < 16) {
      asm volatile("s_waitcnt vmcnt(0)" ::: "memory");  // own stage landed
      __builtin_amdgcn_s_barrier();
      asm volatile("" ::: "memory");
    }
  }

  // ---- t-split merge: A's partials -> LDS (aliases K/V, dead now); B adds.
  __syncthreads();  // all waves done computing before mrg overwrites K/V
  if (g == 0) {
    float* mp = sm.mrg + (wg * 64 + lane) * 35;
#pragma unroll
    for (int s = 0; s < 2; ++s)
#pragma unroll
      for (int j = 0; j < 4; ++j)
#pragma unroll
        for (int r = 0; r < 4; ++r) mp[s * 16 + j * 4 + r] = acc_o[s][j][r];
    mp[32] = l_part[0];
    mp[33] = l_part[1];
  }
  __syncthreads();
  if (g == 1) {
    const float* mp = sm.mrg + (wg * 64 + lane) * 35;
#pragma unroll
    for (int s = 0; s < 2; ++s)
#pragma unroll
      for (int j = 0; j < 4; ++j)
#pragma unroll
        for (int r = 0; r < 4; ++r) acc_o[s][j][r] += mp[s * 16 + j * 4 + r];
    l_part[0] += mp[32];
    l_part[1] += mp[33];

#pragma unroll
    for (int s = 0; s < 2; ++s) {
      float l = l_part[s];
      l += __shfl_xor(l, 16, 64);
      l += __shfl_xor(l, 32, 64);
      float rl[4];
#pragma unroll
      for (int r = 0; r < 4; ++r) rl[r] = 1.0f / __shfl(l, qsrc[r], 64);
#pragma unroll
      for (int j = 0; j < 4; ++j)
#pragma unroll
        for (int r = 0; r < 4; ++r) {
          const int row = b * Sz + q0 + wg * 32 + s * 16 + fq * 4 + r;
          const int col = h * 64 + j * 16 + fr;
          ctx[(size_t)row * Dz + col] = (bf16)(acc_o[s][j][r] * rl[r]);
        }
    }
  }
}

// =====================================================================
// LayerNorm: one wave per row of 512. bf16 input; fp32 or bf16 output.
// =====================================================================
template <int OUT_F32>
__global__ __launch_bounds__(256) void layer_norm_k(
    const bf16* __restrict__ y, const float* __restrict__ g,
    const float* __restrict__ be, void* __restrict__ out) {
  const int row = blockIdx.x * 4 + (threadIdx.x >> 6);
  const int lane = threadIdx.x & 63;
  const int col = lane * 8;
  bf16x8 hv = *(const bf16x8*)(y + (size_t)row * Dz + col);
  float v[8];
  float s = 0.f, ss = 0.f;
#pragma unroll
  for (int i = 0; i < 8; ++i) {
    v[i] = (float)hv[i];
    s += v[i];
    ss += v[i] * v[i];
  }
#pragma unroll
  for (int o = 1; o < 64; o <<= 1) {
    s += __shfl_xor(s, o, 64);
    ss += __shfl_xor(ss, o, 64);
  }
  const float mu = s * (1.0f / Dz);
  const float rstd = rsqrtf(ss * (1.0f / Dz) - mu * mu + EPSf);
  const float4* g4 = (const float4*)(g + col);
  const float4* b4 = (const float4*)(be + col);
  float4 ga = g4[0], gb = g4[1], ba = b4[0], bb = b4[1];
  float o8[8];
  o8[0] = (v[0] - mu) * rstd * ga.x + ba.x;
  o8[1] = (v[1] - mu) * rstd * ga.y + ba.y;
  o8[2] = (v[2] - mu) * rstd * ga.z + ba.z;
  o8[3] = (v[3] - mu) * rstd * ga.w + ba.w;
  o8[4] = (v[4] - mu) * rstd * gb.x + bb.x;
  o8[5] = (v[5] - mu) * rstd * gb.y + bb.y;
  o8[6] = (v[6] - mu) * rstd * gb.z + bb.z;
  o8[7] = (v[7] - mu) * rstd * gb.w + bb.w;
  if (OUT_F32) {
    float4* of = (float4*)((float*)out + (size_t)row * Dz + col);
    of[0] = make_float4(o8[0], o8[1], o8[2], o8[3]);
    of[1] = make_float4(o8[4], o8[5], o8[6], o8[7]);
  } else {
    bf16 ob[8];
#pragma unroll
    for (int i = 0; i < 8; ++i) ob[i] = (bf16)o8[i];
    *(uint4*)((bf16*)out + (size_t)row * Dz + col) = *(const uint4*)ob;
  }
}

// =====================================================================
// Fused prep: all 6 weight transposes (fp32[K,N] -> bf16[N,K], 64x64
// tiles), bias concat, x -> bf16 cast. One launch.
// =====================================================================
__global__ __launch_bounds__(256) void prep_all(
    const float* __restrict__ Wq, const float* __restrict__ Wk,
    const float* __restrict__ Wv, const float* __restrict__ Wo,
    const float* __restrict__ W1, const float* __restrict__ W2,
    const float* __restrict__ bq, const float* __restrict__ bk,
    const float* __restrict__ bv, const float* __restrict__ x,
    bf16* __restrict__ WqkvT, bf16* __restrict__ WoT,
    bf16* __restrict__ W1T, bf16* __restrict__ W2T,
    float* __restrict__ bqkv, bf16* __restrict__ xb) {
  __shared__ float tile[64][65];
  const int blk = blockIdx.x;
  const int t = threadIdx.x;
  if (blk < 768) {
    const float* W;
    bf16* Wt;
    int K, N, local;
    if (blk < 64)       { W = Wq; Wt = WqkvT;                       K = 512;  N = 512;  local = blk; }
    else if (blk < 128) { W = Wk; Wt = WqkvT + (size_t)512 * 512;   K = 512;  N = 512;  local = blk - 64; }
    else if (blk < 192) { W = Wv; Wt = WqkvT + (size_t)1024 * 512;  K = 512;  N = 512;  local = blk - 128; }
    else if (blk < 256) { W = Wo; Wt = WoT;                         K = 512;  N = 512;  local = blk - 192; }
    else if (blk < 512) { W = W1; Wt = W1T;                         K = 512;  N = 2048; local = blk - 256; }
    else                { W = W2; Wt = W2T;                         K = 2048; N = 512;  local = blk - 512; }
    const int kt = K / 64;
    const int k0 = (local % kt) * 64, n0 = (local / kt) * 64;
    const int r = t >> 2, c = (t & 3) * 16;
    const float* src = W + (size_t)(k0 + r) * N + n0 + c;
#pragma unroll
    for (int i = 0; i < 4; ++i) {
      float4 v = ((const float4*)src)[i];
      tile[r][c + i * 4 + 0] = v.x;
      tile[r][c + i * 4 + 1] = v.y;
      tile[r][c + i * 4 + 2] = v.z;
      tile[r][c + i * 4 + 3] = v.w;
    }
    __syncthreads();
    union { bf16 hh[16]; uint4 u[2]; } pk;
#pragma unroll
    for (int i = 0; i < 16; ++i) pk.hh[i] = (bf16)tile[c + i][r];
    uint4* dst = (uint4*)(Wt + (size_t)(n0 + r) * K + k0 + c);
    dst[0] = pk.u[0];
    dst[1] = pk.u[1];
  } else if (blk == 768) {
    for (int i = t; i < 1536; i += 256)
      bqkv[i] = i < 512 ? bq[i] : (i < 1024 ? bk[i - 512] : bv[i - 1024]);
  } else {
    const int local = blk - 769;  // 0..1023, each handles 1024 float4s
#pragma unroll
    for (int k = 0; k < 4; ++k) {
      const int i = local * 1024 + k * 256 + t;
      float4 v = ((const float4*)x)[i];
      bf16 tv[4] = {(bf16)v.x, (bf16)v.y, (bf16)v.z, (bf16)v.w};
      ((uint2*)xb)[i] = *(const uint2*)tv;
    }
  }
}

// =====================================================================
extern "C" void kernel_launch(void* const* d_in, const int* in_sizes, int n_in,
                              void* d_out, int out_size, void* d_ws, size_t ws_size,
                              hipStream_t stream) {
  const float* x   = (const float*)d_in[0];
  const float* Wq  = (const float*)d_in[1];
  const float* bq  = (const float*)d_in[2];
  const float* Wk  = (const float*)d_in[3];
  const float* bk  = (const float*)d_in[4];
  const float* Wv  = (const float*)d_in[5];
  const float* bvp = (const float*)d_in[6];
  const float* Wo  = (const float*)d_in[7];
  const float* bo  = (const float*)d_in[8];
  const float* W1  = (const float*)d_in[9];
  const float* b1  = (const float*)d_in[10];
  const float* W2  = (const float*)d_in[11];
  const float* b2  = (const float*)d_in[12];
  const float* g1  = (const float*)d_in[13];
  const float* be1 = (const float*)d_in[14];
  const float* g2  = (const float*)d_in[15];
  const float* be2 = (const float*)d_in[16];

  char* ws = (char*)d_ws;
  size_t off = 0;
  auto alloc = [&](size_t bytes) -> void* {
    void* p = ws + off;
    off += (bytes + 255) & ~(size_t)255;
    return p;
  };
  bf16*  WqkvT = (bf16*)alloc((size_t)1536 * 512 * 2);
  float* bqkv  = (float*)alloc(1536 * 4);
  bf16*  WoT   = (bf16*)alloc((size_t)512 * 512 * 2);
  bf16*  W1T   = (bf16*)alloc((size_t)2048 * 512 * 2);
  bf16*  W2T   = (bf16*)alloc((size_t)512 * 2048 * 2);
  bf16*  xb    = (bf16*)alloc((size_t)ROWSz * 512 * 2);
  bf16*  qkv   = (bf16*)alloc((size_t)ROWSz * 1536 * 2);    // 24 MB (Q,K rows)
  bf16*  Vt    = (bf16*)alloc((size_t)32 * 64 * 2048 * 2);  // 8 MB, written by QKV epilogue
  bf16*  ctx   = (bf16*)alloc((size_t)ROWSz * 512 * 2);
  bf16*  y1    = (bf16*)alloc((size_t)ROWSz * 512 * 2);     // Wo+resid out (bf16)
  bf16*  x1b   = (bf16*)alloc((size_t)ROWSz * 512 * 2);     // LN1 out
  bf16*  hbuf  = qkv;  // 32 MB alias over qkv+Vt (dead after attention+Wo)
  bf16*  y2    = y1;   // dead after LN1

  // fused prep (weights, bias concat, x cast)
  prep_all<<<dim3(1793), 256, 0, stream>>>(Wq, Wk, Wv, Wo, W1, W2, bq, bk, bvp, x,
                                           WqkvT, WoT, W1T, W2T, bqkv, xb);

  // QKV projection (fused N=1536; Q cols pre-scaled by C2; V cols -> Vt transposed)
  gemm_bt<128, 32, 3><<<dim3(12, 64), 256, 0, stream>>>(xb, WqkvT, bqkv, nullptr, nullptr, Vt, qkv, ROWSz, 1536, 512);
  // attention (512 blocks x 8 waves; 32q/wave, t-split A:0-15 B:16-31)
  flash_attn<<<dim3(512), 512, 0, stream>>>(qkv, Vt, ctx);
  // Wo + bias + residual(xb bf16) -> y1 bf16
  gemm_bt<64, 64, 4><<<dim3(4, 128), 256, 0, stream>>>(ctx, WoT, bo, nullptr, xb, nullptr, y1, ROWSz, 512, 512);
  layer_norm_k<0><<<dim3(2048), 256, 0, stream>>>(y1, g1, be1, x1b);
  // FFN1: 128x256 deep-pipelined tile (512 blocks = 2/CU, 4 waves/SIMD)
  gemm_256<<<dim3(8, 64), 512, 0, stream>>>(x1b, W1T, b1, hbuf, ROWSz, 2048, 512);
  gemm_bt<64, 64, 4><<<dim3(4, 128), 256, 0, stream>>>(hbuf, W2T, b2, nullptr, x1b, nullptr, y2, ROWSz, 512, 2048);
  layer_norm_k<1><<<dim3(2048), 256, 0, stream>>>(y2, g2, be2, d_out);
}

// Round 15
// 231.878 us; speedup vs baseline: 1.0229x; 1.0229x over previous
//
#include <hip/hip_runtime.h>
#include <hip/hip_bf16.h>
#include <stdint.h>

typedef __bf16 bf16;
typedef __attribute__((ext_vector_type(8))) __bf16 bf16x8;
typedef __attribute__((ext_vector_type(4))) float f32x4;

#define DEVI __device__ __forceinline__

constexpr int Bz = 4, Sz = 2048, Dz = 512, Hz = 8, DKz = 64, DFFz = 2048;
constexpr int ROWSz = Bz * Sz;  // 8192
constexpr float EPSf = 1e-5f;
constexpr float C2f = 0.125f * 1.44269504088896f;  // 1/sqrt(DK) * log2(e)

// ---- async global->LDS, 16B per lane. LDS dest is wave-uniform base + lane*16.
DEVI void load_lds16(void* lds, const void* g) {
  __builtin_amdgcn_global_load_lds(
      (const __attribute__((address_space(1))) void*)(uintptr_t)(g),
      (__attribute__((address_space(3))) void*)(uint32_t)(uintptr_t)(lds),
      16, 0, 0);
}

// gfx950 cross-lane half-swaps (pure VALU; all lanes active in this kernel).
DEVI void permswap32(unsigned& x, unsigned& y) {
  asm("v_permlane32_swap_b32 %0, %1" : "+v"(x), "+v"(y));
}
DEVI void permswap16(unsigned& x, unsigned& y) {
  asm("v_permlane16_swap_b32 %0, %1" : "+v"(x), "+v"(y));
}

// T1 XCD-aware block remap (R13, measured -9.3us on the GEMM fleet).
// HW round-robins linear block id over 8 XCDs (xcd = lid%8). Remap so
// each XCD owns a CONTIGUOUS sid range sweeping bx fastest: blocks
// sharing an A row-panel (same by) land on one XCD -> A-panel + weight
// panel become XCD-L2-resident. Bijective when nblocks%8==0.
DEVI void xcd_remap(int& bx, int& by) {
  const int gx = gridDim.x;
  const int nb = gx * gridDim.y;
  const int lid = blockIdx.y * gx + blockIdx.x;
  const int per = nb >> 3;  // nb % 8 == 0 at every call site
  const int sid = (lid & 7) * per + (lid >> 3);
  bx = sid % gx;
  by = sid / gx;
}

// =====================================================================
// GEMM (best measured mix):  C = A[M,K] @ Bt[N,K]^T  +bias.
// EPI 2: bf16 = relu(acc+bias)
// EPI 3: QKV: col<512 Q*C2 row-major; col<1024 K row-major;
//        col>=1024 V -> aux = Vt transposed (LDS transpose epilogue).
// =====================================================================
template <int BM, int BK, int EPI>
__global__ __launch_bounds__(256, BM == 128 ? 4 : 3) void gemm_bt(
    const bf16* __restrict__ A, const bf16* __restrict__ Bt,
    const float* __restrict__ bias, const float* __restrict__ resid,
    const bf16* __restrict__ residb, bf16* __restrict__ aux,
    void* __restrict__ Cout, int M, int N, int K) {
  constexpr int BN = 128;
  constexpr int MI = BM / 32;          // m-frags per wave
  constexpr int RPI = 512 / BK;        // rows per 16B-issue (16 @BK32, 8 @BK64)
  constexpr int AISS = (BM / 4) / RPI; // A issues per wave
  constexpr int BISS = 32 / RPI;       // B issues per wave
  __shared__ alignas(16) bf16 sA[2][BM * BK];
  __shared__ alignas(16) bf16 sB[2][BN * BK];
  const int tid = threadIdx.x;
  const int lane = tid & 63;
  const int wv = tid >> 6;
  int bx, by;
  xcd_remap(bx, by);
  const int n0 = bx * BN;
  const int m0 = by * BM;

  const int srow = (BK == 32) ? (lane >> 2) : (lane >> 3);
  const int sch = (BK == 32) ? (((lane & 3) ^ (srow & 3)) * 8)
                             : (((lane & 7) ^ (srow & 7)) * 8);
  const bf16* gA = A + (size_t)(m0 + wv * (BM / 4) + srow) * K + sch;
  const bf16* gB = Bt + (size_t)(n0 + wv * 32 + srow) * K + sch;

  const int wm = (wv >> 1) * (BM / 2);
  const int wn = (wv & 1) * 64;
  const int fr = lane & 15;
  const int fq = lane >> 4;

  auto stage = [&](int buf, int k0) {
#pragma unroll
    for (int j = 0; j < AISS; ++j)
      load_lds16(sA[buf] + (wv * (BM / 4) + j * RPI) * BK, gA + (size_t)(j * RPI) * K + k0);
#pragma unroll
    for (int j = 0; j < BISS; ++j)
      load_lds16(sB[buf] + (wv * 32 + j * RPI) * BK, gB + (size_t)(j * RPI) * K + k0);
  };

  f32x4 acc[MI][4] = {};

  stage(0, 0);
  __syncthreads();  // barrier's vmcnt(0) drain completes tile 0

  const int niter = K / BK;
  for (int it = 0; it < niter; ++it) {
    const int cur = it & 1;
    if (it + 1 < niter) stage(cur ^ 1, (it + 1) * BK);
#pragma unroll
    for (int kk = 0; kk < BK / 32; ++kk) {
      const int fc = (BK == 32) ? ((fq ^ (fr & 3)) * 8)
                                : (((4 * kk + fq) ^ (fr & 7)) * 8);
      bf16x8 af[MI], bfr[4];
#pragma unroll
      for (int i = 0; i < MI; ++i)
        af[i] = *(const bf16x8*)(sA[cur] + (wm + i * 16 + fr) * BK + fc);
#pragma unroll
      for (int j = 0; j < 4; ++j)
        bfr[j] = *(const bf16x8*)(sB[cur] + (wn + j * 16 + fr) * BK + fc);
#pragma unroll
      for (int i = 0; i < MI; ++i)
#pragma unroll
        for (int j = 0; j < 4; ++j)
          acc[i][j] = __builtin_amdgcn_mfma_f32_16x16x32_bf16(af[i], bfr[j], acc[i][j], 0, 0, 0);
    }
    __syncthreads();  // readers done with cur + prefetch DMA drained
  }

  if (EPI == 3 && n0 >= 1024) {
    // ---- V epilogue: per-wave LDS transpose -> coalesced Vt stores.
    bf16* Tw = (wv < 2 ? (bf16*)sA : (bf16*)sB) + (wv & 1) * 4096;  // 8KB own
#pragma unroll
    for (int i = 0; i < MI; ++i) {
#pragma unroll
      for (int j = 0; j < 4; ++j) {
        const int col = n0 + wn + j * 16 + fr;
        const float bv = bias[col];
        bf16 pv[4];
#pragma unroll
        for (int r = 0; r < 4; ++r) pv[r] = (bf16)(acc[i][j][r] + bv);
        const int dk = j * 16 + fr;
        const int boff = dk * 128 + ((i * 32 + fq * 8) ^ ((fr & 7) << 4));
        *(uint2*)((char*)Tw + boff) = *(const uint2*)pv;
      }
    }
    asm volatile("s_waitcnt lgkmcnt(0)" ::: "memory");  // own writes visible
    const int hh = (n0 + wn - 1024) >> 6;
    const int rowbase = m0 + wm;
    const int bb = rowbase >> 11, s0b = rowbase & 2047;
#pragma unroll
    for (int p = 0; p < 8; ++p) {
      const int dk = p * 8 + (lane >> 3);
      const int o = lane & 7;
      const uint4 v = *(const uint4*)((const char*)Tw + dk * 128 + ((o ^ (dk & 7)) << 4));
      *(uint4*)(aux + (size_t)((bb * 8 + hh) * 64 + dk) * 2048 + s0b + o * 8) = v;
    }
  } else {
#pragma unroll
    for (int i = 0; i < MI; ++i) {
#pragma unroll
      for (int j = 0; j < 4; ++j) {
        const int col = n0 + wn + j * 16 + fr;
        const float bv = bias[col];
#pragma unroll
        for (int r = 0; r < 4; ++r) {
          const int row = m0 + wm + i * 16 + fq * 4 + r;
          const size_t idx = (size_t)row * N + col;
          float v = acc[i][j][r] + bv;
          if (EPI == 1) {
            ((bf16*)Cout)[idx] = (bf16)(v + resid[idx]);
          } else if (EPI == 2) {
            ((bf16*)Cout)[idx] = (bf16)(v > 0.f ? v : 0.f);
          } else if (EPI == 3) {
            ((bf16*)Cout)[idx] = (bf16)(col < 512 ? v * C2f : v);
          } else {
            ((bf16*)Cout)[idx] = (bf16)(v + (float)residb[idx]);
          }
        }
      }
    }
  }
}

// =====================================================================
// gemm_bt3 (R15): tail GEMMs (Wo K=512, FFN2 K=2048), EPI=4 semantics
// (bf16 = acc + bias + bf16resid). Identical tile/fragments/grid/
// epilogue to gemm_bt<64,64,4> (byte-inherited algebra, XCD remap),
// but THREE LDS buffers (72KB) + counted vmcnt(6): per tile 6 issues/
// wave (A x2 + B x4); stage(t+2) at tile top writes buf (t-1)%3 whose
// reads completed before the end-of-(t-1) barrier; end-of-t vmcnt(6)
// retires t+1's 6 loads, keeps t+2's in flight (NEVER 0 mid-loop);
// tail drains vmcnt(0) at t=niter-2. T4 mechanism scales with niter:
// FFN2's 32 iterations is the most favorable site in the network.
// LDS 72KB -> 2 blocks/CU = the grid limit anyway (512 blocks).
// =====================================================================
__global__ __launch_bounds__(256, 2) void gemm_bt3(
    const bf16* __restrict__ A, const bf16* __restrict__ Bt,
    const float* __restrict__ bias, const bf16* __restrict__ residb,
    bf16* __restrict__ Cout, int M, int N, int K) {
  constexpr int BM = 64, BK = 64, BN = 128;
  constexpr int MI = 2;
  __shared__ alignas(16) bf16 sA[3][BM * BK];  // 8KB each
  __shared__ alignas(16) bf16 sB[3][BN * BK];  // 16KB each
  const int tid = threadIdx.x;
  const int lane = tid & 63;
  const int wv = tid >> 6;
  int bx, by;
  xcd_remap(bx, by);
  const int n0 = bx * BN;
  const int m0 = by * BM;

  const int srow = lane >> 3;                      // 0..7
  const int sch = ((lane & 7) ^ (srow & 7)) * 8;   // pre-swizzled chunk
  const bf16* gA = A + (size_t)(m0 + wv * 16 + srow) * K + sch;
  const bf16* gB = Bt + (size_t)(n0 + wv * 32 + srow) * K + sch;

  const int wm = (wv >> 1) * 32;
  const int wn = (wv & 1) * 64;
  const int fr = lane & 15;
  const int fq = lane >> 4;

  auto stage = [&](int buf, int k0) {
#pragma unroll
    for (int j = 0; j < 2; ++j)  // A: 2 issues x 8 rows
      load_lds16(sA[buf] + (wv * 16 + j * 8) * BK, gA + (size_t)(j * 8) * K + k0);
#pragma unroll
    for (int j = 0; j < 4; ++j)  // B: 4 issues x 8 rows
      load_lds16(sB[buf] + (wv * 32 + j * 8) * BK, gB + (size_t)(j * 8) * K + k0);
  };

  f32x4 acc[MI][4] = {};

  // prologue: tiles 0,1 staged (12 issues); tile 0's 6 retired
  stage(0, 0);
  stage(1, BK);
  asm volatile("s_waitcnt vmcnt(6)" ::: "memory");
  __builtin_amdgcn_s_barrier();
  asm volatile("" ::: "memory");

  const int niter = K / BK;  // 8 for Wo, 32 for FFN2
  int cur = 0;
  for (int t = 0; t < niter; ++t) {
    int nb = cur + 2;
    if (nb >= 3) nb -= 3;
    const bool pf = (t + 2 < niter);
    if (pf) stage(nb, (t + 2) * BK);

#pragma unroll
    for (int kk = 0; kk < 2; ++kk) {
      const int fc = (((4 * kk + fq) ^ (fr & 7)) * 8);
      bf16x8 af[MI], bfr[4];
#pragma unroll
      for (int i = 0; i < MI; ++i)
        af[i] = *(const bf16x8*)(sA[cur] + (wm + i * 16 + fr) * BK + fc);
#pragma unroll
      for (int j = 0; j < 4; ++j)
        bfr[j] = *(const bf16x8*)(sB[cur] + (wn + j * 16 + fr) * BK + fc);
      __builtin_amdgcn_s_setprio(1);
#pragma unroll
      for (int i = 0; i < MI; ++i)
#pragma unroll
        for (int j = 0; j < 4; ++j)
          acc[i][j] = __builtin_amdgcn_mfma_f32_16x16x32_bf16(af[i], bfr[j], acc[i][j], 0, 0, 0);
      __builtin_amdgcn_s_setprio(0);
    }

    if (t + 1 < niter) {
      if (pf) asm volatile("s_waitcnt vmcnt(6)" ::: "memory");  // t+1 ready
      else    asm volatile("s_waitcnt vmcnt(0)" ::: "memory");  // drain tail
      __builtin_amdgcn_s_barrier();
      asm volatile("" ::: "memory");
    }
    cur = cur == 2 ? 0 : cur + 1;
  }

  // ---- epilogue: acc + bias + bf16resid (same mapping as gemm_bt EPI=4)
#pragma unroll
  for (int i = 0; i < MI; ++i)
#pragma unroll
    for (int j = 0; j < 4; ++j) {
      const int col = n0 + wn + j * 16 + fr;
      const float bv = bias[col];
#pragma unroll
      for (int r = 0; r < 4; ++r) {
        const int row = m0 + wm + i * 16 + fq * 4 + r;
        const size_t idx = (size_t)row * N + col;
        float v = acc[i][j][r] + bv;
        Cout[idx] = (bf16)(v + (float)residb[idx]);
      }
    }
}

// =====================================================================
// Deep-pipelined GEMM v2 (R14, FFN1): C = relu(A @ Bt^T + bias).
// BM=128/BN=256, grid 8x64 = 512 blocks = 2/CU = 4 waves/SIMD.
// 3-buffer counted-vmcnt ledger (3 issues/tile: A x1 + B x2).
// =====================================================================
__global__ __launch_bounds__(512, 4) void gemm_256(
    const bf16* __restrict__ A, const bf16* __restrict__ Bt,
    const float* __restrict__ bias, bf16* __restrict__ Cout,
    int M, int N, int K) {
  constexpr int BM = 128, BN = 256, BK = 32;
  __shared__ alignas(16) bf16 sA[3][BM * BK];  // 8KB each
  __shared__ alignas(16) bf16 sB[3][BN * BK];  // 16KB each
  const int tid = threadIdx.x, lane = tid & 63, wv = tid >> 6;  // wv 0..7
  const int wr = wv >> 2, wc = wv & 3;  // wave -> 64x64 output sub-tile
  int bx, by;
  xcd_remap(bx, by);
  const int n0 = bx * BN, m0 = by * BM;
  const int fr = lane & 15, fq = lane >> 4;

  // staging: one issue covers 128 rows (8 waves x 16)
  const int srow = lane >> 2;                      // 0..15
  const int sch = ((lane & 3) ^ (srow & 3)) * 8;   // pre-swizzled chunk
  const bf16* gA = A + (size_t)(m0 + wv * 16 + srow) * K + sch;
  const bf16* gB = Bt + (size_t)(n0 + wv * 16 + srow) * K + sch;

  auto stageA = [&](int buf, int k0) {
    load_lds16(sA[buf] + (wv * 16) * BK, gA + k0);
  };
  auto stageB = [&](int buf, int k0) {
    load_lds16(sB[buf] + (wv * 16) * BK, gB + k0);
    load_lds16(sB[buf] + (128 + wv * 16) * BK, gB + (size_t)128 * K + k0);
  };

  const int fc = (fq ^ (fr & 3)) * 8;  // read-side swizzle (row&3 == fr&3)

  f32x4 acc[4][4] = {};

  // prologue: tiles 0,1 staged (6 issues); tile 0's 3 retired
  stageA(0, 0);
  stageB(0, 0);
  stageA(1, BK);
  stageB(1, BK);
  asm volatile("s_waitcnt vmcnt(3)" ::: "memory");
  __builtin_amdgcn_s_barrier();
  asm volatile("" ::: "memory");

  const int niter = K / BK;  // 16 for FFN1
  int cur = 0;
  for (int t = 0; t < niter; ++t) {
    const bf16* a = sA[cur];
    const bf16* b = sB[cur];
    int nb = cur + 2;
    if (nb >= 3) nb -= 3;
    const bool pf = (t + 2 < niter);

    // ---- phase 0: B-frags (all 4, reused) + A-frags 0-1; stage A(t+2)
    bf16x8 bfr[4], af[2];
#pragma unroll
    for (int j = 0; j < 4; ++j)
      bfr[j] = *(const bf16x8*)(b + (wc * 64 + j * 16 + fr) * BK + fc);
#pragma unroll
    for (int i = 0; i < 2; ++i)
      af[i] = *(const bf16x8*)(a + (wr * 64 + i * 16 + fr) * BK + fc);
    if (pf) stageA(nb, (t + 2) * BK);
    __builtin_amdgcn_s_setprio(1);
#pragma unroll
    for (int i = 0; i < 2; ++i)
#pragma unroll
      for (int j = 0; j < 4; ++j)
        acc[i][j] = __builtin_amdgcn_mfma_f32_16x16x32_bf16(af[i], bfr[j], acc[i][j], 0, 0, 0);
    __builtin_amdgcn_s_setprio(0);
    __builtin_amdgcn_s_barrier();  // phase alignment
    asm volatile("" ::: "memory");

    // ---- phase 1: A-frags 2-3; stage B(t+2); tile-end counted sync
    bf16x8 af2[2];
#pragma unroll
    for (int i = 0; i < 2; ++i)
      af2[i] = *(const bf16x8*)(a + (wr * 64 + (2 + i) * 16 + fr) * BK + fc);
    if (pf) stageB(nb, (t + 2) * BK);
    __builtin_amdgcn_s_setprio(1);
#pragma unroll
    for (int i = 0; i < 2; ++i)
#pragma unroll
      for (int j = 0; j < 4; ++j)
        acc[2 + i][j] = __builtin_amdgcn_mfma_f32_16x16x32_bf16(af2[i], bfr[j], acc[2 + i][j], 0, 0, 0);
    __builtin_amdgcn_s_setprio(0);
    if (t + 1 < niter) {
      if (pf) asm volatile("s_waitcnt vmcnt(3)" ::: "memory");  // t+1 ready
      else    asm volatile("s_waitcnt vmcnt(0)" ::: "memory");  // drain tail
      __builtin_amdgcn_s_barrier();
      asm volatile("" ::: "memory");
    }
    cur = cur == 2 ? 0 : cur + 1;
  }

  // ---- epilogue: relu(acc + bias) -> bf16 (same mapping as gemm_bt)
#pragma unroll
  for (int i = 0; i < 4; ++i)
#pragma unroll
    for (int j = 0; j < 4; ++j) {
      const int col = n0 + wc * 64 + j * 16 + fr;
      const float bv = bias[col];
#pragma unroll
      for (int r = 0; r < 4; ++r) {
        const int row = m0 + wr * 64 + i * 16 + fq * 4 + r;
        float v = acc[i][j][r] + bv;
        Cout[(size_t)row * N + col] = (bf16)(v > 0.f ? v : 0.f);
      }
    }
}

// =====================================================================
// Flash attention v8 (R8, frozen best: 50.0us): t-split + 32 q/wave.
// 8-wave blocks: waves 0-3 tiles 0-15, waves 4-7 tiles 16-31, same
// 128 q-rows; partials merged via LDS (max-free softmax => pure sums).
// Grid 512, 16 waves/CU = 4/SIMD.
// =====================================================================
__global__ __launch_bounds__(512, 4) void flash_attn(
    const bf16* __restrict__ qkv, const bf16* __restrict__ Vt,
    bf16* __restrict__ ctx) {
  const int bid = blockIdx.x;
  const int qt = bid >> 5;         // 0..15, 128-row q tiles
  const int bh = bid & 31;         // bid%8 == h -> XCD pinning per head
  const int h = bh & 7;
  const int b = bh >> 3;
  const int q0 = qt * 128;
  const int tid = threadIdx.x, lane = tid & 63, wv = tid >> 6;  // wv 0..7
  const int g = wv >> 2;           // t-group: 0 -> tiles 0..15, 1 -> 16..31
  const int wg = wv & 3;           // wave in group; owns q rows wg*32..+31
  const int fr = lane & 15, fq = lane >> 4;
  const int xsw = fr & 7;

  __shared__ alignas(16) union SMem {
    struct { bf16 K[2][2][64 * 64]; bf16 V[2][2][64 * 64]; } kv;
    float mrg[4 * 64 * 35];  // 4 waves x 64 lanes x (32 acc + 2 l + pad)
  } sm;

  const int srow = lane >> 3;                // 0..7 within 8-row issue
  const int scol = ((lane & 7) ^ srow) * 8;  // swizzled chunk (elements)

  const bf16* gK = qkv + (size_t)(b * Sz + wg * 16 + srow) * 1536 + 512 + h * 64 + scol;
  const bf16* gV = Vt + (size_t)((b * 8 + h) * 64 + wg * 16 + srow) * Sz + scol;

  auto stage = [&](int p, int t) {
    const size_t t0 = (size_t)t * 64;
    load_lds16(sm.kv.K[g][p] + (wg * 16 + 0) * 64, gK + t0 * 1536);
    load_lds16(sm.kv.K[g][p] + (wg * 16 + 8) * 64, gK + (t0 + 8) * 1536);
    load_lds16(sm.kv.V[g][p] + (wg * 16 + 0) * 64, gV + t0);
    load_lds16(sm.kv.V[g][p] + (wg * 16 + 8) * 64, gV + (size_t)8 * Sz + t0);
  };

  stage(0, g * 16);  // tile 0 of own range

  const bf16* gQf = qkv + (size_t)(b * Sz + q0 + wg * 32 + fr) * 1536 + h * 64;
  bf16x8 qb[2][2];
  qb[0][0] = *(const bf16x8*)(gQf + fq * 8);
  qb[0][1] = *(const bf16x8*)(gQf + (fq + 4) * 8);
  qb[1][0] = *(const bf16x8*)(gQf + (size_t)16 * 1536 + fq * 8);
  qb[1][1] = *(const bf16x8*)(gQf + (size_t)16 * 1536 + (fq + 4) * 8);

  asm volatile("s_waitcnt vmcnt(0)" ::: "memory");  // qb + stage(0) landed
  __builtin_amdgcn_s_barrier();
  asm volatile("" ::: "memory");

  const int colc0 = (fq ^ xsw) * 8;
  const int colc1 = ((fq + 4) ^ xsw) * 8;
  int qsrc[4];
#pragma unroll
  for (int r = 0; r < 4; ++r) qsrc[r] = (fq * 4 + r) | (lane & 48);

  const f32x4 ZERO = {0.f, 0.f, 0.f, 0.f};
  float l_part[2] = {0.f, 0.f};
  f32x4 acc_o[2][4] = {};

  for (int st = 0; st < 16; ++st) {
    const int p = st & 1;
    if (st + 1 < 16) stage(p ^ 1, g * 16 + st + 1);

    const bf16* kb = sm.kv.K[g][p];
    const bf16* vb = sm.kv.V[g][p];

    bf16x8 kf[2][4];
#pragma unroll
    for (int j = 0; j < 4; ++j) {
      kf[0][j] = *(const bf16x8*)(kb + (j * 16 + fr) * 64 + colc0);
      kf[1][j] = *(const bf16x8*)(kb + (j * 16 + fr) * 64 + colc1);
    }
    f32x4 sc[2][4];
    __builtin_amdgcn_s_setprio(1);
#pragma unroll
    for (int s = 0; s < 2; ++s)
#pragma unroll
      for (int j = 0; j < 4; ++j) {
        f32x4 z = __builtin_amdgcn_mfma_f32_16x16x32_bf16(kf[0][j], qb[s][0], ZERO, 0, 0, 0);
        sc[s][j] = __builtin_amdgcn_mfma_f32_16x16x32_bf16(kf[1][j], qb[s][1], z, 0, 0, 0);
      }
    __builtin_amdgcn_s_setprio(0);

    bf16x8 pa[2][2];
#pragma unroll
    for (int s = 0; s < 2; ++s) {
      unsigned c0[4], c1[4];
      float rs = 0.f;
#pragma unroll
      for (int j = 0; j < 4; ++j) {
        float e0 = __builtin_amdgcn_exp2f(sc[s][j][0]);
        float e1 = __builtin_amdgcn_exp2f(sc[s][j][1]);
        float e2 = __builtin_amdgcn_exp2f(sc[s][j][2]);
        float e3 = __builtin_amdgcn_exp2f(sc[s][j][3]);
        rs += (e0 + e1) + (e2 + e3);
        union { bf16 hh[2]; unsigned u; } pka, pkb;
        pka.hh[0] = (bf16)e0; pka.hh[1] = (bf16)e1;  // v_cvt_pk_bf16_f32
        pkb.hh[0] = (bf16)e2; pkb.hh[1] = (bf16)e3;
        c0[j] = pka.u;
        c1[j] = pkb.u;
      }
      l_part[s] += rs;
#pragma unroll
      for (int kk = 0; kk < 2; ++kk) {
        unsigned x0 = c0[2 * kk], y0 = c0[2 * kk + 1];
        permswap32(x0, y0);
        permswap16(x0, y0);
        unsigned x1 = c1[2 * kk], y1 = c1[2 * kk + 1];
        permswap32(x1, y1);
        permswap16(x1, y1);
        union { unsigned u[4]; bf16x8 v; } pk;
        pk.u[0] = x0; pk.u[1] = x1; pk.u[2] = y0; pk.u[3] = y1;
        pa[s][kk] = pk.v;
      }
    }

    bf16x8 vf[2][4];
#pragma unroll
    for (int j = 0; j < 4; ++j) {
      vf[0][j] = *(const bf16x8*)(vb + (j * 16 + fr) * 64 + colc0);
      vf[1][j] = *(const bf16x8*)(vb + (j * 16 + fr) * 64 + colc1);
    }
    __builtin_amdgcn_s_setprio(1);
#pragma unroll
    for (int s = 0; s < 2; ++s)
#pragma unroll
      for (int kk = 0; kk < 2; ++kk)
#pragma unroll
        for (int j = 0; j < 4; ++j)
          acc_o[s][j] = __builtin_amdgcn_mfma_f32_16x16x32_bf16(pa[s][kk], vf[kk][j], acc_o[s][j], 0, 0, 0);
    __builtin_amdgcn_s_setprio(0);

    if (st + 1 < 16) {
      asm volatile("s_waitcnt vmcnt(0)" ::: "memory");  // own stage landed
      __builtin_amdgcn_s_barrier();
      asm volatile("" ::: "memory");
    }
  }

  // ---- t-split merge: A's partials -> LDS (aliases K/V, dead now); B adds.
  __syncthreads();  // all waves done computing before mrg overwrites K/V
  if (g == 0) {
    float* mp = sm.mrg + (wg * 64 + lane) * 35;
#pragma unroll
    for (int s = 0; s < 2; ++s)
#pragma unroll
      for (int j = 0; j < 4; ++j)
#pragma unroll
        for (int r = 0; r < 4; ++r) mp[s * 16 + j * 4 + r] = acc_o[s][j][r];
    mp[32] = l_part[0];
    mp[33] = l_part[1];
  }
  __syncthreads();
  if (g == 1) {
    const float* mp = sm.mrg + (wg * 64 + lane) * 35;
#pragma unroll
    for (int s = 0; s < 2; ++s)
#pragma unroll
      for (int j = 0; j < 4; ++j)
#pragma unroll
        for (int r = 0; r < 4; ++r) acc_o[s][j][r] += mp[s * 16 + j * 4 + r];
    l_part[0] += mp[32];
    l_part[1] += mp[33];

#pragma unroll
    for (int s = 0; s < 2; ++s) {
      float l = l_part[s];
      l += __shfl_xor(l, 16, 64);
      l += __shfl_xor(l, 32, 64);
      float rl[4];
#pragma unroll
      for (int r = 0; r < 4; ++r) rl[r] = 1.0f / __shfl(l, qsrc[r], 64);
#pragma unroll
      for (int j = 0; j < 4; ++j)
#pragma unroll
        for (int r = 0; r < 4; ++r) {
          const int row = b * Sz + q0 + wg * 32 + s * 16 + fq * 4 + r;
          const int col = h * 64 + j * 16 + fr;
          ctx[(size_t)row * Dz + col] = (bf16)(acc_o[s][j][r] * rl[r]);
        }
    }
  }
}

// =====================================================================
// LayerNorm: one wave per row of 512. bf16 input; fp32 or bf16 output.
// =====================================================================
template <int OUT_F32>
__global__ __launch_bounds__(256) void layer_norm_k(
    const bf16* __restrict__ y, const float* __restrict__ g,
    const float* __restrict__ be, void* __restrict__ out) {
  const int row = blockIdx.x * 4 + (threadIdx.x >> 6);
  const int lane = threadIdx.x & 63;
  const int col = lane * 8;
  bf16x8 hv = *(const bf16x8*)(y + (size_t)row * Dz + col);
  float v[8];
  float s = 0.f, ss = 0.f;
#pragma unroll
  for (int i = 0; i < 8; ++i) {
    v[i] = (float)hv[i];
    s += v[i];
    ss += v[i] * v[i];
  }
#pragma unroll
  for (int o = 1; o < 64; o <<= 1) {
    s += __shfl_xor(s, o, 64);
    ss += __shfl_xor(ss, o, 64);
  }
  const float mu = s * (1.0f / Dz);
  const float rstd = rsqrtf(ss * (1.0f / Dz) - mu * mu + EPSf);
  const float4* g4 = (const float4*)(g + col);
  const float4* b4 = (const float4*)(be + col);
  float4 ga = g4[0], gb = g4[1], ba = b4[0], bb = b4[1];
  float o8[8];
  o8[0] = (v[0] - mu) * rstd * ga.x + ba.x;
  o8[1] = (v[1] - mu) * rstd * ga.y + ba.y;
  o8[2] = (v[2] - mu) * rstd * ga.z + ba.z;
  o8[3] = (v[3] - mu) * rstd * ga.w + ba.w;
  o8[4] = (v[4] - mu) * rstd * gb.x + bb.x;
  o8[5] = (v[5] - mu) * rstd * gb.y + bb.y;
  o8[6] = (v[6] - mu) * rstd * gb.z + bb.z;
  o8[7] = (v[7] - mu) * rstd * gb.w + bb.w;
  if (OUT_F32) {
    float4* of = (float4*)((float*)out + (size_t)row * Dz + col);
    of[0] = make_float4(o8[0], o8[1], o8[2], o8[3]);
    of[1] = make_float4(o8[4], o8[5], o8[6], o8[7]);
  } else {
    bf16 ob[8];
#pragma unroll
    for (int i = 0; i < 8; ++i) ob[i] = (bf16)o8[i];
    *(uint4*)((bf16*)out + (size_t)row * Dz + col) = *(const uint4*)ob;
  }
}

// =====================================================================
// Fused prep: all 6 weight transposes (fp32[K,N] -> bf16[N,K], 64x64
// tiles), bias concat, x -> bf16 cast. One launch.
// =====================================================================
__global__ __launch_bounds__(256) void prep_all(
    const float* __restrict__ Wq, const float* __restrict__ Wk,
    const float* __restrict__ Wv, const float* __restrict__ Wo,
    const float* __restrict__ W1, const float* __restrict__ W2,
    const float* __restrict__ bq, const float* __restrict__ bk,
    const float* __restrict__ bv, const float* __restrict__ x,
    bf16* __restrict__ WqkvT, bf16* __restrict__ WoT,
    bf16* __restrict__ W1T, bf16* __restrict__ W2T,
    float* __restrict__ bqkv, bf16* __restrict__ xb) {
  __shared__ float tile[64][65];
  const int blk = blockIdx.x;
  const int t = threadIdx.x;
  if (blk < 768) {
    const float* W;
    bf16* Wt;
    int K, N, local;
    if (blk < 64)       { W = Wq; Wt = WqkvT;                       K = 512;  N = 512;  local = blk; }
    else if (blk < 128) { W = Wk; Wt = WqkvT + (size_t)512 * 512;   K = 512;  N = 512;  local = blk - 64; }
    else if (blk < 192) { W = Wv; Wt = WqkvT + (size_t)1024 * 512;  K = 512;  N = 512;  local = blk - 128; }
    else if (blk < 256) { W = Wo; Wt = WoT;                         K = 512;  N = 512;  local = blk - 192; }
    else if (blk < 512) { W = W1; Wt = W1T;                         K = 512;  N = 2048; local = blk - 256; }
    else                { W = W2; Wt = W2T;                         K = 2048; N = 512;  local = blk - 512; }
    const int kt = K / 64;
    const int k0 = (local % kt) * 64, n0 = (local / kt) * 64;
    const int r = t >> 2, c = (t & 3) * 16;
    const float* src = W + (size_t)(k0 + r) * N + n0 + c;
#pragma unroll
    for (int i = 0; i < 4; ++i) {
      float4 v = ((const float4*)src)[i];
      tile[r][c + i * 4 + 0] = v.x;
      tile[r][c + i * 4 + 1] = v.y;
      tile[r][c + i * 4 + 2] = v.z;
      tile[r][c + i * 4 + 3] = v.w;
    }
    __syncthreads();
    union { bf16 hh[16]; uint4 u[2]; } pk;
#pragma unroll
    for (int i = 0; i < 16; ++i) pk.hh[i] = (bf16)tile[c + i][r];
    uint4* dst = (uint4*)(Wt + (size_t)(n0 + r) * K + k0 + c);
    dst[0] = pk.u[0];
    dst[1] = pk.u[1];
  } else if (blk == 768) {
    for (int i = t; i < 1536; i += 256)
      bqkv[i] = i < 512 ? bq[i] : (i < 1024 ? bk[i - 512] : bv[i - 1024]);
  } else {
    const int local = blk - 769;  // 0..1023, each handles 1024 float4s
#pragma unroll
    for (int k = 0; k < 4; ++k) {
      const int i = local * 1024 + k * 256 + t;
      float4 v = ((const float4*)x)[i];
      bf16 tv[4] = {(bf16)v.x, (bf16)v.y, (bf16)v.z, (bf16)v.w};
      ((uint2*)xb)[i] = *(const uint2*)tv;
    }
  }
}

// =====================================================================
extern "C" void kernel_launch(void* const* d_in, const int* in_sizes, int n_in,
                              void* d_out, int out_size, void* d_ws, size_t ws_size,
                              hipStream_t stream) {
  const float* x   = (const float*)d_in[0];
  const float* Wq  = (const float*)d_in[1];
  const float* bq  = (const float*)d_in[2];
  const float* Wk  = (const float*)d_in[3];
  const float* bk  = (const float*)d_in[4];
  const float* Wv  = (const float*)d_in[5];
  const float* bvp = (const float*)d_in[6];
  const float* Wo  = (const float*)d_in[7];
  const float* bo  = (const float*)d_in[8];
  const float* W1  = (const float*)d_in[9];
  const float* b1  = (const float*)d_in[10];
  const float* W2  = (const float*)d_in[11];
  const float* b2  = (const float*)d_in[12];
  const float* g1  = (const float*)d_in[13];
  const float* be1 = (const float*)d_in[14];
  const float* g2  = (const float*)d_in[15];
  const float* be2 = (const float*)d_in[16];

  char* ws = (char*)d_ws;
  size_t off = 0;
  auto alloc = [&](size_t bytes) -> void* {
    void* p = ws + off;
    off += (bytes + 255) & ~(size_t)255;
    return p;
  };
  bf16*  WqkvT = (bf16*)alloc((size_t)1536 * 512 * 2);
  float* bqkv  = (float*)alloc(1536 * 4);
  bf16*  WoT   = (bf16*)alloc((size_t)512 * 512 * 2);
  bf16*  W1T   = (bf16*)alloc((size_t)2048 * 512 * 2);
  bf16*  W2T   = (bf16*)alloc((size_t)512 * 2048 * 2);
  bf16*  xb    = (bf16*)alloc((size_t)ROWSz * 512 * 2);
  bf16*  qkv   = (bf16*)alloc((size_t)ROWSz * 1536 * 2);    // 24 MB (Q,K rows)
  bf16*  Vt    = (bf16*)alloc((size_t)32 * 64 * 2048 * 2);  // 8 MB, written by QKV epilogue
  bf16*  ctx   = (bf16*)alloc((size_t)ROWSz * 512 * 2);
  bf16*  y1    = (bf16*)alloc((size_t)ROWSz * 512 * 2);     // Wo+resid out (bf16)
  bf16*  x1b   = (bf16*)alloc((size_t)ROWSz * 512 * 2);     // LN1 out
  bf16*  hbuf  = qkv;  // 32 MB alias over qkv+Vt (dead after attention+Wo)
  bf16*  y2    = y1;   // dead after LN1

  // fused prep (weights, bias concat, x cast)
  prep_all<<<dim3(1793), 256, 0, stream>>>(Wq, Wk, Wv, Wo, W1, W2, bq, bk, bvp, x,
                                           WqkvT, WoT, W1T, W2T, bqkv, xb);

  // QKV projection (fused N=1536; Q cols pre-scaled by C2; V cols -> Vt transposed)
  gemm_bt<128, 32, 3><<<dim3(12, 64), 256, 0, stream>>>(xb, WqkvT, bqkv, nullptr, nullptr, Vt, qkv, ROWSz, 1536, 512);
  // attention (512 blocks x 8 waves; 32q/wave, t-split A:0-15 B:16-31)
  flash_attn<<<dim3(512), 512, 0, stream>>>(qkv, Vt, ctx);
  // Wo + bias + residual(xb bf16) -> y1 bf16   [3-buffer counted vmcnt]
  gemm_bt3<<<dim3(4, 128), 256, 0, stream>>>(ctx, WoT, bo, xb, y1, ROWSz, 512, 512);
  layer_norm_k<0><<<dim3(2048), 256, 0, stream>>>(y1, g1, be1, x1b);
  // FFN1: 128x256 deep-pipelined tile (512 blocks = 2/CU, 4 waves/SIMD)
  gemm_256<<<dim3(8, 64), 512, 0, stream>>>(x1b, W1T, b1, hbuf, ROWSz, 2048, 512);
  // FFN2 + bias + residual(x1b) -> y2 bf16     [3-buffer counted vmcnt, K=2048]
  gemm_bt3<<<dim3(4, 128), 256, 0, stream>>>(hbuf, W2T, b2, x1b, y2, ROWSz, 512, 2048);
  layer_norm_k<1><<<dim3(2048), 256, 0, stream>>>(y2, g2, be2, d_out);
}